// Round 1
// baseline (986.577 us; speedup 1.0000x reference)
//
#include <hip/hip_runtime.h>
#include <math.h>

#define NROWS 4096
#define DDIM  128
#define IMG_ELEMS 50331648LL   // 4096*3*64*64
#define TILE 64
#define KC 32
#define LSTR 36                // 32 + 4 pad: i-frags conflict-free, j-frags 2-way (free)

// ws layout (doubles): [0]=mse_sum [1]=kld_sum [2]=Spp [3]=Szz [4]=Spz

__global__ void init_ws_kernel(double* ws) {
    if (threadIdx.x < 8) ws[threadIdx.x] = 0.0;
}

__device__ __forceinline__ void block_reduce_atomic(double v, double* dst) {
    #pragma unroll
    for (int o = 32; o > 0; o >>= 1) v += __shfl_down(v, o);
    __shared__ double sm[4];
    int lane = threadIdx.x & 63, wv = threadIdx.x >> 6;
    if (lane == 0) sm[wv] = v;
    __syncthreads();
    if (threadIdx.x == 0) atomicAdd(dst, sm[0] + sm[1] + sm[2] + sm[3]);
}

__global__ __launch_bounds__(256) void mse_kernel(const float4* __restrict__ r,
                                                  const float4* __restrict__ x,
                                                  double* __restrict__ ws) {
    const long long n4 = IMG_ELEMS / 4;
    const long long stride = (long long)gridDim.x * 256;
    float acc = 0.f;
    for (long long i = (long long)blockIdx.x * 256 + threadIdx.x; i < n4; i += stride) {
        float4 a = r[i], b = x[i];
        float dx = a.x - b.x, dy = a.y - b.y, dz = a.z - b.z, dw = a.w - b.w;
        acc += dx * dx + dy * dy + dz * dz + dw * dw;
    }
    block_reduce_atomic((double)acc, &ws[0]);
}

__global__ __launch_bounds__(256) void kld_kernel(const float4* __restrict__ mu,
                                                  const float4* __restrict__ lv,
                                                  double* __restrict__ ws) {
    int i = blockIdx.x * 256 + threadIdx.x;  // exactly NROWS*DDIM/4 threads
    float4 m = mu[i], l = lv[i];
    float s = (1.f + l.x - m.x * m.x - expf(l.x))
            + (1.f + l.y - m.y * m.y - expf(l.y))
            + (1.f + l.z - m.z * m.z - expf(l.z))
            + (1.f + l.w - m.w * m.w - expf(l.w));
    block_reduce_atomic((double)s, &ws[1]);
}

// Computes partial sums of Kpp, Kzz, Kpz over a 64x64 tile of pairs.
// P = prior_z, Z = z. k_ij = exp(c*(2*dot - n_i - n_j)), c = 1/65536.
__global__ __launch_bounds__(256) void mmd_kernel(const float* __restrict__ P,
                                                  const float* __restrict__ Z,
                                                  double* __restrict__ ws) {
    __shared__ float stage[4][TILE * LSTR];   // [pi, zi, pj, zj]
    __shared__ float nrm[4][TILE];            // row norms, same order
    __shared__ double red[3][4];

    const int tid = threadIdx.x;
    const int tx = tid & 15;   // j-fragment group
    const int ty = tid >> 4;   // i-fragment group
    const int i0 = blockIdx.y * TILE;
    const int j0 = blockIdx.x * TILE;

    // init norm accumulators: thread owns (buf = tid>>6, slot = tid&63)
    nrm[tid >> 6][tid & 63] = 0.f;

    float app[4][4] = {}, azz[4][4] = {}, apz[4][4] = {};

    const int srow = tid >> 2;     // 0..63 staging row
    const int sq   = tid & 3;      // 0..3  staging quad

    for (int kc = 0; kc < DDIM; kc += KC) {
        __syncthreads();   // previous-chunk readers done (and norm init visible)
        {
            const float* gA = P + (size_t)(i0 + srow) * DDIM + kc;
            const float* gB = Z + (size_t)(i0 + srow) * DDIM + kc;
            const float* gC = P + (size_t)(j0 + srow) * DDIM + kc;
            const float* gD = Z + (size_t)(j0 + srow) * DDIM + kc;
            float* dA = &stage[0][srow * LSTR];
            float* dB = &stage[1][srow * LSTR];
            float* dC = &stage[2][srow * LSTR];
            float* dD = &stage[3][srow * LSTR];
            *(float4*)(dA + sq * 4)      = *(const float4*)(gA + sq * 4);
            *(float4*)(dA + 16 + sq * 4) = *(const float4*)(gA + 16 + sq * 4);
            *(float4*)(dB + sq * 4)      = *(const float4*)(gB + sq * 4);
            *(float4*)(dB + 16 + sq * 4) = *(const float4*)(gB + 16 + sq * 4);
            *(float4*)(dC + sq * 4)      = *(const float4*)(gC + sq * 4);
            *(float4*)(dC + 16 + sq * 4) = *(const float4*)(gC + 16 + sq * 4);
            *(float4*)(dD + sq * 4)      = *(const float4*)(gD + sq * 4);
            *(float4*)(dD + 16 + sq * 4) = *(const float4*)(gD + 16 + sq * 4);
        }
        __syncthreads();

        // per-row norm partials: thread exclusively owns (buf, slot)
        {
            const int slot = tid & 63, buf = tid >> 6;
            const float* rp = &stage[buf][slot * LSTR];
            float s = 0.f;
            #pragma unroll
            for (int d = 0; d < KC; d += 4) {
                float4 v = *(const float4*)(rp + d);
                s += v.x * v.x + v.y * v.y + v.z * v.z + v.w * v.w;
            }
            nrm[buf][slot] += s;
        }

        // 4x4 register-tiled triple gram
        #pragma unroll
        for (int d = 0; d < KC; d += 4) {
            float4 pi[4], zi[4], pj[4], zj[4];
            #pragma unroll
            for (int k = 0; k < 4; k++) {
                pi[k] = *(const float4*)&stage[0][(ty + 16 * k) * LSTR + d];
                zi[k] = *(const float4*)&stage[1][(ty + 16 * k) * LSTR + d];
                pj[k] = *(const float4*)&stage[2][(tx + 16 * k) * LSTR + d];
                zj[k] = *(const float4*)&stage[3][(tx + 16 * k) * LSTR + d];
            }
            #pragma unroll
            for (int a = 0; a < 4; a++) {
                #pragma unroll
                for (int b = 0; b < 4; b++) {
                    app[a][b] += pi[a].x * pj[b].x + pi[a].y * pj[b].y
                               + pi[a].z * pj[b].z + pi[a].w * pj[b].w;
                    azz[a][b] += zi[a].x * zj[b].x + zi[a].y * zj[b].y
                               + zi[a].z * zj[b].z + zi[a].w * zj[b].w;
                    apz[a][b] += pi[a].x * zj[b].x + pi[a].y * zj[b].y
                               + pi[a].z * zj[b].z + pi[a].w * zj[b].w;
                }
            }
        }
    }
    __syncthreads();   // norms complete

    const float cc = 1.0f / 65536.0f;   // 1/(D * 2*D*z_var)
    float spp = 0.f, szz = 0.f, spz = 0.f;
    #pragma unroll
    for (int a = 0; a < 4; a++) {
        const int ii = ty + 16 * a;
        const float npi = nrm[0][ii], nzi = nrm[1][ii];
        #pragma unroll
        for (int b = 0; b < 4; b++) {
            const int jj = tx + 16 * b;
            spp += expf(cc * (2.f * app[a][b] - npi - nrm[2][jj]));
            szz += expf(cc * (2.f * azz[a][b] - nzi - nrm[3][jj]));
            spz += expf(cc * (2.f * apz[a][b] - npi - nrm[3][jj]));
        }
    }

    double vpp = spp, vzz = szz, vpz = spz;
    #pragma unroll
    for (int o = 32; o > 0; o >>= 1) {
        vpp += __shfl_down(vpp, o);
        vzz += __shfl_down(vzz, o);
        vpz += __shfl_down(vpz, o);
    }
    const int lane = tid & 63, wv = tid >> 6;
    if (lane == 0) { red[0][wv] = vpp; red[1][wv] = vzz; red[2][wv] = vpz; }
    __syncthreads();
    if (tid == 0) {
        atomicAdd(&ws[2], red[0][0] + red[0][1] + red[0][2] + red[0][3]);
        atomicAdd(&ws[3], red[1][0] + red[1][1] + red[1][2] + red[1][3]);
        atomicAdd(&ws[4], red[2][0] + red[2][1] + red[2][2] + red[2][3]);
    }
}

__global__ void finalize_kernel(const double* __restrict__ ws, float* __restrict__ out) {
    if (threadIdx.x == 0) {
        const double Nd = (double)NROWS;
        double recons_loss = ws[0] / (double)IMG_ELEMS;
        double kld = -0.5 * ws[1] / Nd;                       // mean over rows of -0.5*rowsum
        double mmd = (ws[2] + ws[3] - 2.0 * ws[4]) / (Nd * Nd);
        double bias_corr = Nd * (Nd - 1.0);
        double loss = 5.0 * recons_loss               // BETA
                    + 1.5 * (1.0 / Nd) * kld          // (1-ALPHA)*kld_weight
                    + (98.5 / bias_corr) * mmd;       // (ALPHA+REG_WEIGHT-1)/bias_corr
        out[0] = (float)loss;
        out[1] = (float)recons_loss;
        out[2] = (float)mmd;
        out[3] = (float)(-kld);
    }
}

extern "C" void kernel_launch(void* const* d_in, const int* in_sizes, int n_in,
                              void* d_out, int out_size, void* d_ws, size_t ws_size,
                              hipStream_t stream) {
    const float* recons  = (const float*)d_in[0];
    const float* x       = (const float*)d_in[1];
    const float* z       = (const float*)d_in[2];
    const float* mu      = (const float*)d_in[3];
    const float* log_var = (const float*)d_in[4];
    const float* prior_z = (const float*)d_in[5];
    double* ws = (double*)d_ws;
    float* out = (float*)d_out;

    init_ws_kernel<<<1, 64, 0, stream>>>(ws);
    mse_kernel<<<2048, 256, 0, stream>>>((const float4*)recons, (const float4*)x, ws);
    kld_kernel<<<(NROWS * DDIM / 4) / 256, 256, 0, stream>>>((const float4*)mu,
                                                             (const float4*)log_var, ws);
    mmd_kernel<<<dim3(NROWS / TILE, NROWS / TILE), 256, 0, stream>>>(prior_z, z, ws);
    finalize_kernel<<<1, 64, 0, stream>>>(ws, out);
}

// Round 2
// 490.551 us; speedup vs baseline: 2.0112x; 2.0112x over previous
//
#include <hip/hip_runtime.h>
#include <math.h>

#define NROWS 4096
#define DDIM  128
#define IMG_ELEMS 50331648LL   // 4096*3*64*64

typedef __attribute__((ext_vector_type(8))) short short8;   // 8 bf16 = 4 VGPRs
typedef __attribute__((ext_vector_type(4))) float floatx4;  // MFMA acc

// ws layout (bytes):
//   [0,64)        : 5 doubles  [0]=mse [1]=kld [2]=Spp [3]=Szz [4]=Spz
//   [64, +16K)    : nP (4096 f32 row norms of prior_z)
//   [.. , +16K)   : nZ
//   then 4 x 1MB  : Phi, Plo, Zhi, Zlo (bf16 as ushort, 4096x128 row-major)
#define WS_NP   64
#define WS_NZ   (WS_NP + 16384)
#define WS_PHI  (WS_NZ + 16384)
#define WS_PLO  (WS_PHI + 1048576)
#define WS_ZHI  (WS_PLO + 1048576)
#define WS_ZLO  (WS_ZHI + 1048576)

__device__ __forceinline__ unsigned short f2bf(float f) {
    unsigned u = __float_as_uint(f);
    unsigned r = (u + 0x7FFFu + ((u >> 16) & 1u)) >> 16;   // RNE
    return (unsigned short)r;
}
__device__ __forceinline__ float bf2f(unsigned short h) {
    return __uint_as_float(((unsigned)h) << 16);
}

__device__ __forceinline__ void async_ld16(const void* g, void* l) {
    __builtin_amdgcn_global_load_lds(
        (const __attribute__((address_space(1))) unsigned int*)g,
        (__attribute__((address_space(3))) unsigned int*)l, 16, 0, 0);
}

__global__ void init_ws_kernel(double* ws) {
    if (threadIdx.x < 8) ws[threadIdx.x] = 0.0;
}

__device__ __forceinline__ void block_reduce_atomic(double v, double* dst) {
    #pragma unroll
    for (int o = 32; o > 0; o >>= 1) v += __shfl_down(v, o);
    __shared__ double sm[4];
    int lane = threadIdx.x & 63, wv = threadIdx.x >> 6;
    if (lane == 0) sm[wv] = v;
    __syncthreads();
    if (threadIdx.x == 0) atomicAdd(dst, sm[0] + sm[1] + sm[2] + sm[3]);
}

// One wave per row (8192 rows total: P then Z). Splits fp32 -> bf16 hi+lo,
// computes exact fp32 row norms.
__global__ __launch_bounds__(64) void prep_kernel(const float* __restrict__ P,
                                                  const float* __restrict__ Z,
                                                  char* __restrict__ wsb) {
    const int b = blockIdx.x;            // 0..8191
    const int row = b & 4095;
    const float* src;
    unsigned short *hi, *lo;
    float* nrm;
    if (b < 4096) {
        src = P + (size_t)row * DDIM;
        hi = (unsigned short*)(wsb + WS_PHI) + (size_t)row * DDIM;
        lo = (unsigned short*)(wsb + WS_PLO) + (size_t)row * DDIM;
        nrm = (float*)(wsb + WS_NP);
    } else {
        src = Z + (size_t)row * DDIM;
        hi = (unsigned short*)(wsb + WS_ZHI) + (size_t)row * DDIM;
        lo = (unsigned short*)(wsb + WS_ZLO) + (size_t)row * DDIM;
        nrm = (float*)(wsb + WS_NZ);
    }
    const int l = threadIdx.x;           // 0..63
    float2 v = ((const float2*)src)[l];
    unsigned short hx = f2bf(v.x), hy = f2bf(v.y);
    unsigned short lx = f2bf(v.x - bf2f(hx)), ly = f2bf(v.y - bf2f(hy));
    ((ushort2*)hi)[l] = make_ushort2(hx, hy);
    ((ushort2*)lo)[l] = make_ushort2(lx, ly);
    float s = v.x * v.x + v.y * v.y;
    #pragma unroll
    for (int o = 32; o > 0; o >>= 1) s += __shfl_down(s, o);
    if (l == 0) nrm[row] = s;
}

__global__ __launch_bounds__(256) void mse_kernel(const float4* __restrict__ r,
                                                  const float4* __restrict__ x,
                                                  double* __restrict__ ws) {
    const long long n4 = IMG_ELEMS / 4;
    const long long stride = (long long)gridDim.x * 256;
    float acc = 0.f;
    for (long long i = (long long)blockIdx.x * 256 + threadIdx.x; i < n4; i += stride) {
        float4 a = r[i], b = x[i];
        float dx = a.x - b.x, dy = a.y - b.y, dz = a.z - b.z, dw = a.w - b.w;
        acc += dx * dx + dy * dy + dz * dz + dw * dw;
    }
    block_reduce_atomic((double)acc, &ws[0]);
}

__global__ __launch_bounds__(256) void kld_kernel(const float4* __restrict__ mu,
                                                  const float4* __restrict__ lv,
                                                  double* __restrict__ ws) {
    int i = blockIdx.x * 256 + threadIdx.x;
    float4 m = mu[i], l = lv[i];
    float s = (1.f + l.x - m.x * m.x - expf(l.x))
            + (1.f + l.y - m.y * m.y - expf(l.y))
            + (1.f + l.z - m.z * m.z - expf(l.z))
            + (1.f + l.w - m.w * m.w - expf(l.w));
    block_reduce_atomic((double)s, &ws[1]);
}

// 128x128 C-tile per block, 4 waves, each wave a 64x64 quadrant of 4x4
// mfma_f32_16x16x32_bf16 subtiles. K = 3 hi/lo passes x 128.
// blockIdx.z = gram type: 0=pp, 1=zz, 2=pz. Sums exp(kernel) into ws[2+g].
__global__ __launch_bounds__(256) void gram_kernel(char* __restrict__ wsb,
                                                   double* __restrict__ ws) {
    __shared__ __align__(16) unsigned short sA[128 * 32];
    __shared__ __align__(16) unsigned short sB[128 * 32];

    const int g = blockIdx.z;
    const unsigned short *Ahi, *Alo, *Bhi, *Blo;
    const float *nI, *nJ;
    const unsigned short* Phi = (const unsigned short*)(wsb + WS_PHI);
    const unsigned short* Plo = (const unsigned short*)(wsb + WS_PLO);
    const unsigned short* Zhi = (const unsigned short*)(wsb + WS_ZHI);
    const unsigned short* Zlo = (const unsigned short*)(wsb + WS_ZLO);
    const float* nP = (const float*)(wsb + WS_NP);
    const float* nZ = (const float*)(wsb + WS_NZ);
    if (g == 0)      { Ahi = Phi; Alo = Plo; Bhi = Phi; Blo = Plo; nI = nP; nJ = nP; }
    else if (g == 1) { Ahi = Zhi; Alo = Zlo; Bhi = Zhi; Blo = Zlo; nI = nZ; nJ = nZ; }
    else             { Ahi = Phi; Alo = Plo; Bhi = Zhi; Blo = Zlo; nI = nP; nJ = nZ; }

    const int i0 = blockIdx.y * 128, j0 = blockIdx.x * 128;
    const int tid = threadIdx.x, lane = tid & 63, w = tid >> 6;
    const int qi = (w >> 1) * 64, qj = (w & 1) * 64;

    floatx4 acc[4][4];
    const floatx4 zero4 = {0.f, 0.f, 0.f, 0.f};
    #pragma unroll
    for (int a = 0; a < 4; a++)
        #pragma unroll
        for (int b = 0; b < 4; b++) acc[a][b] = zero4;

    const int fr = lane & 15, fq = lane >> 4;

    #pragma unroll
    for (int pass = 0; pass < 3; pass++) {
        const unsigned short* As = (pass == 2) ? Alo : Ahi;  // hi,hi,lo
        const unsigned short* Bs = (pass == 1) ? Blo : Bhi;  // hi,lo,hi
        for (int kc = 0; kc < DDIM; kc += 32) {
            __syncthreads();   // readers of previous chunk done
            #pragma unroll
            for (int t = 0; t < 2; t++) {
                // wave-inst covers 1024B contiguous LDS: base=(t*4+w)*1024 + lane*16
                const int r  = ((t * 4 + w) << 4) + (lane >> 2);
                const int ko = (lane & 3) * 8;                       // bf16 elems
                async_ld16(As + (size_t)(i0 + r) * DDIM + kc + ko,
                           (char*)sA + r * 64 + ko * 2);
                async_ld16(Bs + (size_t)(j0 + r) * DDIM + kc + ko,
                           (char*)sB + r * 64 + ko * 2);
            }
            __syncthreads();   // vmcnt(0) drain before barrier completes staging

            short8 af[4], bf[4];
            #pragma unroll
            for (int a = 0; a < 4; a++)
                af[a] = *(const short8*)((const char*)sA + (qi + a * 16 + fr) * 64 + fq * 16);
            #pragma unroll
            for (int b = 0; b < 4; b++)
                bf[b] = *(const short8*)((const char*)sB + (qj + b * 16 + fr) * 64 + fq * 16);
            #pragma unroll
            for (int a = 0; a < 4; a++)
                #pragma unroll
                for (int b = 0; b < 4; b++)
                    acc[a][b] = __builtin_amdgcn_mfma_f32_16x16x32_bf16(
                        af[a], bf[b], acc[a][b], 0, 0, 0);
        }
    }

    // epilogue: k_ij = exp(cc*(2*dot - ni - nj)), cc = 1/(D * 2*D*z_var)
    const float cc = 1.0f / 65536.0f;
    float nj_[4];
    #pragma unroll
    for (int b = 0; b < 4; b++) nj_[b] = nJ[j0 + qj + b * 16 + fr];
    float sum = 0.f;
    #pragma unroll
    for (int a = 0; a < 4; a++) {
        #pragma unroll
        for (int r = 0; r < 4; r++) {
            const float ni = nI[i0 + qi + a * 16 + fq * 4 + r];
            #pragma unroll
            for (int b = 0; b < 4; b++)
                sum += expf(cc * (2.f * acc[a][b][r] - ni - nj_[b]));
        }
    }

    double v = (double)sum;
    #pragma unroll
    for (int o = 32; o > 0; o >>= 1) v += __shfl_down(v, o);
    __shared__ double red[4];
    if (lane == 0) red[w] = v;
    __syncthreads();
    if (tid == 0) atomicAdd(&ws[2 + g], red[0] + red[1] + red[2] + red[3]);
}

__global__ void finalize_kernel(const double* __restrict__ ws, float* __restrict__ out) {
    if (threadIdx.x == 0) {
        const double Nd = (double)NROWS;
        double recons_loss = ws[0] / (double)IMG_ELEMS;
        double kld = -0.5 * ws[1] / Nd;
        double mmd = (ws[2] + ws[3] - 2.0 * ws[4]) / (Nd * Nd);
        double bias_corr = Nd * (Nd - 1.0);
        double loss = 5.0 * recons_loss
                    + 1.5 * (1.0 / Nd) * kld
                    + (98.5 / bias_corr) * mmd;
        out[0] = (float)loss;
        out[1] = (float)recons_loss;
        out[2] = (float)mmd;
        out[3] = (float)(-kld);
    }
}

extern "C" void kernel_launch(void* const* d_in, const int* in_sizes, int n_in,
                              void* d_out, int out_size, void* d_ws, size_t ws_size,
                              hipStream_t stream) {
    const float* recons  = (const float*)d_in[0];
    const float* x       = (const float*)d_in[1];
    const float* z       = (const float*)d_in[2];
    const float* mu      = (const float*)d_in[3];
    const float* log_var = (const float*)d_in[4];
    const float* prior_z = (const float*)d_in[5];
    double* ws = (double*)d_ws;
    char* wsb = (char*)d_ws;
    float* out = (float*)d_out;

    init_ws_kernel<<<1, 64, 0, stream>>>(ws);
    prep_kernel<<<8192, 64, 0, stream>>>(prior_z, z, wsb);
    mse_kernel<<<2048, 256, 0, stream>>>((const float4*)recons, (const float4*)x, ws);
    kld_kernel<<<(NROWS * DDIM / 4) / 256, 256, 0, stream>>>((const float4*)mu,
                                                             (const float4*)log_var, ws);
    gram_kernel<<<dim3(NROWS / 128, NROWS / 128, 3), 256, 0, stream>>>(wsb, ws);
    finalize_kernel<<<1, 64, 0, stream>>>(ws, out);
}